// Round 1
// baseline (382.398 us; speedup 1.0000x reference)
//
#include <hip/hip_runtime.h>
#include <hip/hip_bf16.h>

#define S_LEN  512
#define D_DIM  64
#define BH_N   256
#define NH     16
#define R_LEN  1023
#define BHD    16384          // BH_N * D_DIM
#define PITCH  72             // bf16 LDS tile pitch: 144 B rows, 16B aligned, 2-way banks
#define BPITCH 65             // fp32 bias tile pitch

typedef __attribute__((ext_vector_type(8))) short   short8_t;
typedef __attribute__((ext_vector_type(8))) __bf16  bf16x8;
typedef __attribute__((ext_vector_type(4))) float   floatx4;

__device__ __forceinline__ unsigned short f2bf(float f) {
  union { float f; unsigned u; } v; v.f = f;
  return (unsigned short)((v.u + 0x7fffu + ((v.u >> 16) & 1u)) >> 16);  // RNE
}

__device__ __forceinline__ bf16x8 ldfrag(const unsigned short* p) {
  short8_t s = *(const short8_t*)p;              // ds_read_b128 (16B aligned)
  return __builtin_bit_cast(bf16x8, s);
}

extern "C" __global__ __launch_bounds__(256, 2)
void attn_relbias(const float* __restrict__ q, const float* __restrict__ k,
                  const float* __restrict__ v, const float* __restrict__ emb,
                  float* __restrict__ out)
{
  __shared__ unsigned short qs [64 * PITCH];   // Q tile (bf16)
  __shared__ unsigned short kis[64 * PITCH];   // K rows at i-positions (bias A operand)
  __shared__ unsigned short kjs[64 * PITCH];   // K rows at j-positions
  __shared__ unsigned short vts[64 * PITCH];   // V^T tile: vts[d][j]
  __shared__ unsigned short es [128 * PITCH];  // emb window (127 valid rows + zero row)
  __shared__ float biasp[64 * BPITCH];         // skewed bias tile; reused as bf16 P tile

  const int tid  = threadIdx.x;
  const int bh   = blockIdx.x >> 3;
  const int i0   = (blockIdx.x & 7) << 6;
  const int h    = bh & (NH - 1);
  const int wv   = tid >> 6;          // wave id: owns rows [16*wv, 16*wv+16)
  const int lane = tid & 63;
  const int l15  = lane & 15;
  const int quad = lane >> 4;
  const int iloc0 = wv * 16 + quad * 4;       // +reg -> tile-local row of C elements

  // ---- stage Q tile and K_i tile once ----
  {
    const float* gq = q + (size_t)i0 * BHD + bh * D_DIM;
    const float* gk = k + (size_t)i0 * BHD + bh * D_DIM;
    for (int idx = tid; idx < 1024; idx += 256) {
      int row = idx >> 4, cg = (idx & 15) << 2;
      float4 a = *(const float4*)(gq + row * BHD + cg);
      float4 b = *(const float4*)(gk + row * BHD + cg);
      ushort4 ua = { f2bf(a.x), f2bf(a.y), f2bf(a.z), f2bf(a.w) };
      ushort4 ub = { f2bf(b.x), f2bf(b.y), f2bf(b.z), f2bf(b.w) };
      *(ushort4*)(qs  + row * PITCH + cg) = ua;
      *(ushort4*)(kis + row * PITCH + cg) = ub;
    }
  }
  __syncthreads();

  const int arow = wv * 16 + l15;   // A-operand row for this lane
  const int acol = quad * 8;        // A/B-operand k-offset within 32-wide k-step
  bf16x8 qa0 = ldfrag(qs  + arow * PITCH + acol);
  bf16x8 qa1 = ldfrag(qs  + arow * PITCH + acol + 32);
  bf16x8 ia0 = ldfrag(kis + arow * PITCH + acol);
  bf16x8 ia1 = ldfrag(kis + arow * PITCH + acol + 32);

  floatx4 oacc[4];
  #pragma unroll
  for (int c = 0; c < 4; ++c) oacc[c] = (floatx4){0.f, 0.f, 0.f, 0.f};
  float m_i[4] = { -1e30f, -1e30f, -1e30f, -1e30f };
  float l_i[4] = { 0.f, 0.f, 0.f, 0.f };

  for (int j0 = 0; j0 < S_LEN; j0 += 64) {
    __syncthreads();   // B1: previous iteration's LDS reads (P, Kj, Vt, E) done

    // ---- stage K_j ----
    {
      const float* gk = k + (size_t)j0 * BHD + bh * D_DIM;
      for (int idx = tid; idx < 1024; idx += 256) {
        int row = idx >> 4, cg = (idx & 15) << 2;
        float4 b = *(const float4*)(gk + row * BHD + cg);
        ushort4 ub = { f2bf(b.x), f2bf(b.y), f2bf(b.z), f2bf(b.w) };
        *(ushort4*)(kjs + row * PITCH + cg) = ub;
      }
    }
    // ---- stage V transposed: vts[d][j] ----
    {
      const float* gv = v + (size_t)j0 * BHD + bh * D_DIM;
      for (int idx = tid; idx < 1024; idx += 256) {
        int dg = idx & 15, jl = idx >> 4;
        float4 b = *(const float4*)(gv + jl * BHD + dg * 4);
        int d0 = dg * 4;
        vts[(d0 + 0) * PITCH + jl] = f2bf(b.x);
        vts[(d0 + 1) * PITCH + jl] = f2bf(b.y);
        vts[(d0 + 2) * PITCH + jl] = f2bf(b.z);
        vts[(d0 + 3) * PITCH + jl] = f2bf(b.w);
      }
    }
    // ---- stage emb window: rows r0g .. r0g+126 (row 127 zeroed) ----
    {
      const float* ge = emb + ((size_t)h * R_LEN + (j0 - i0 + 448)) * D_DIM;
      for (int idx = tid; idx < 2048; idx += 256) {
        int row = idx >> 4, cg = (idx & 15) << 2;
        float4 b = { 0.f, 0.f, 0.f, 0.f };
        if (row < 127) b = *(const float4*)(ge + row * D_DIM + cg);
        ushort4 ub = { f2bf(b.x), f2bf(b.y), f2bf(b.z), f2bf(b.w) };
        *(ushort4*)(es + row * PITCH + cg) = ub;
      }
    }
    __syncthreads();   // B2: staging visible

    // ---- bias GEMM: C[iloc][cb] = Ki[iloc]·E[cb], skew-write biasp[iloc][cb+iloc-63] ----
    #pragma unroll
    for (int e = 0; e < 8; ++e) {
      bf16x8 eb0 = ldfrag(es + (e * 16 + l15) * PITCH + acol);
      bf16x8 eb1 = ldfrag(es + (e * 16 + l15) * PITCH + acol + 32);
      floatx4 bacc = (floatx4){0.f, 0.f, 0.f, 0.f};
      bacc = __builtin_amdgcn_mfma_f32_16x16x32_bf16(ia0, eb0, bacc, 0, 0, 0);
      bacc = __builtin_amdgcn_mfma_f32_16x16x32_bf16(ia1, eb1, bacc, 0, 0, 0);
      int cb = e * 16 + l15;
      #pragma unroll
      for (int r = 0; r < 4; ++r) {
        int iloc = iloc0 + r;
        int jl = cb + iloc - 63;
        if (jl >= 0 && jl < 64) biasp[iloc * BPITCH + jl] = bacc[r];
      }
    }

    // ---- QK^T + bias + scale ----
    float sc[4][4];
    #pragma unroll
    for (int c = 0; c < 4; ++c) {
      bf16x8 kb0 = ldfrag(kjs + (c * 16 + l15) * PITCH + acol);
      bf16x8 kb1 = ldfrag(kjs + (c * 16 + l15) * PITCH + acol + 32);
      floatx4 acc = (floatx4){0.f, 0.f, 0.f, 0.f};
      acc = __builtin_amdgcn_mfma_f32_16x16x32_bf16(qa0, kb0, acc, 0, 0, 0);
      acc = __builtin_amdgcn_mfma_f32_16x16x32_bf16(qa1, kb1, acc, 0, 0, 0);
      #pragma unroll
      for (int r = 0; r < 4; ++r)
        sc[c][r] = (acc[r] + biasp[(iloc0 + r) * BPITCH + c * 16 + l15]) * 0.125f;
    }

    // ---- online softmax (row stats live in a 16-lane group) ----
    float p[4][4];
    #pragma unroll
    for (int r = 0; r < 4; ++r) {
      float mx = fmaxf(fmaxf(sc[0][r], sc[1][r]), fmaxf(sc[2][r], sc[3][r]));
      #pragma unroll
      for (int off = 1; off < 16; off <<= 1) mx = fmaxf(mx, __shfl_xor(mx, off));
      float mnew  = fmaxf(m_i[r], mx);
      float alpha = __expf(m_i[r] - mnew);
      float rs = 0.f;
      #pragma unroll
      for (int c = 0; c < 4; ++c) { p[c][r] = __expf(sc[c][r] - mnew); rs += p[c][r]; }
      #pragma unroll
      for (int off = 1; off < 16; off <<= 1) rs += __shfl_xor(rs, off);
      l_i[r] = l_i[r] * alpha + rs;
      m_i[r] = mnew;
      #pragma unroll
      for (int c = 0; c < 4; ++c) oacc[c][r] *= alpha;
    }

    __syncthreads();   // B3: all bias reads done before P overwrites shared buffer

    // ---- P -> LDS (C-layout write), then PV MFMA (A-layout read) ----
    unsigned short* ps = (unsigned short*)biasp;
    #pragma unroll
    for (int c = 0; c < 4; ++c) {
      #pragma unroll
      for (int r = 0; r < 4; ++r)
        ps[(iloc0 + r) * PITCH + c * 16 + l15] = f2bf(p[c][r]);
    }
    bf16x8 pa0 = ldfrag(ps + arow * PITCH + acol);
    bf16x8 pa1 = ldfrag(ps + arow * PITCH + acol + 32);
    #pragma unroll
    for (int c = 0; c < 4; ++c) {
      bf16x8 vb0 = ldfrag(vts + (c * 16 + l15) * PITCH + acol);
      bf16x8 vb1 = ldfrag(vts + (c * 16 + l15) * PITCH + acol + 32);
      oacc[c] = __builtin_amdgcn_mfma_f32_16x16x32_bf16(pa0, vb0, oacc[c], 0, 0, 0);
      oacc[c] = __builtin_amdgcn_mfma_f32_16x16x32_bf16(pa1, vb1, oacc[c], 0, 0, 0);
    }
  }

  // ---- epilogue: O / l, write [s, bh, d] ----
  #pragma unroll
  for (int r = 0; r < 4; ++r) {
    float inv = 1.f / l_i[r];
    int row = i0 + iloc0 + r;
    #pragma unroll
    for (int c = 0; c < 4; ++c)
      out[(size_t)row * BHD + bh * D_DIM + c * 16 + l15] = oacc[c][r] * inv;
  }
}

extern "C" void kernel_launch(void* const* d_in, const int* in_sizes, int n_in,
                              void* d_out, int out_size, void* d_ws, size_t ws_size,
                              hipStream_t stream) {
  const float* q   = (const float*)d_in[0];
  const float* k   = (const float*)d_in[1];
  const float* v   = (const float*)d_in[2];
  const float* emb = (const float*)d_in[3];
  float* out = (float*)d_out;
  hipLaunchKernelGGL(attn_relbias, dim3(2048), dim3(256), 0, stream,
                     q, k, v, emb, out);
}

// Round 2
// 301.228 us; speedup vs baseline: 1.2695x; 1.2695x over previous
//
#include <hip/hip_runtime.h>

#define S_LEN  512
#define D_DIM  64
#define NH     16
#define R_LEN  1023
#define BHD    16384          // BH * D
#define PITCH  72             // bf16 tile pitch (144 B rows, b128-aligned, 2-way free)
#define PPITCH 68             // P tile pitch (136 B rows, b64-aligned, conflict-free writes)

typedef __attribute__((ext_vector_type(8))) short   short8_t;
typedef __attribute__((ext_vector_type(8))) __bf16  bf16x8;
typedef __attribute__((ext_vector_type(4))) float   floatx4;

__device__ __forceinline__ unsigned short f2bf(float f) {
  union { float f; unsigned u; } v; v.f = f;
  return (unsigned short)((v.u + 0x7fffu + ((v.u >> 16) & 1u)) >> 16);  // RNE
}

__device__ __forceinline__ bf16x8 pack8(float4 a, float4 b) {
  union { ushort4 u4[2]; short8_t s8; } u;
  u.u4[0] = (ushort4){ f2bf(a.x), f2bf(a.y), f2bf(a.z), f2bf(a.w) };
  u.u4[1] = (ushort4){ f2bf(b.x), f2bf(b.y), f2bf(b.z), f2bf(b.w) };
  return __builtin_bit_cast(bf16x8, u.s8);
}

__device__ __forceinline__ bf16x8 ldfrag(const unsigned short* p) {   // 16B aligned
  short8_t s = *(const short8_t*)p;
  return __builtin_bit_cast(bf16x8, s);
}

__device__ __forceinline__ bf16x8 ldfrag8(const unsigned short* p) {  // 8B aligned
  union { ushort4 u4[2]; short8_t s8; } u;
  u.u4[0] = *(const ushort4*)p;
  u.u4[1] = *(const ushort4*)(p + 4);
  return __builtin_bit_cast(bf16x8, u.s8);
}

extern "C" __global__ __launch_bounds__(256, 4)
void attn_relbias(const float* __restrict__ q, const float* __restrict__ k,
                  const float* __restrict__ v, const float* __restrict__ emb,
                  float* __restrict__ out)
{
  __shared__ unsigned short kjs[64 * PITCH];        // K_i (pre-loop), then K_j
  __shared__ unsigned short vts[64 * PITCH];        // Q   (pre-loop), then V^T
  __shared__ unsigned short ps [4][16 * PPITCH];    // per-wave P strip

  const int tid  = threadIdx.x;
  const int bh   = blockIdx.x >> 3;
  const int i0   = (blockIdx.x & 7) << 6;
  const int h    = bh & (NH - 1);
  const int wv   = tid >> 6;
  const int lane = tid & 63;
  const int l15  = lane & 15;
  const int quad = lane >> 4;
  const int iloc0 = wv * 16 + quad * 4;
  const int elo   = 3 - wv;           // wave's first bias e-block

  // ---- stage Q -> vts, K_i -> kjs (both dead after frag loads) ----
  {
    const float* gq = q + (size_t)i0 * BHD + bh * D_DIM;
    const float* gk = k + (size_t)i0 * BHD + bh * D_DIM;
    for (int idx = tid; idx < 1024; idx += 256) {
      int row = idx >> 4, cg = (idx & 15) << 2;
      float4 a = *(const float4*)(gq + row * BHD + cg);
      float4 b = *(const float4*)(gk + row * BHD + cg);
      *(ushort4*)(vts + row * PITCH + cg) = (ushort4){ f2bf(a.x), f2bf(a.y), f2bf(a.z), f2bf(a.w) };
      *(ushort4*)(kjs + row * PITCH + cg) = (ushort4){ f2bf(b.x), f2bf(b.y), f2bf(b.z), f2bf(b.w) };
    }
  }
  __syncthreads();

  const int arow = wv * 16 + l15;
  const int acol = quad * 8;
  bf16x8 qa0 = ldfrag(vts + arow * PITCH + acol);
  bf16x8 qa1 = ldfrag(vts + arow * PITCH + acol + 32);
  bf16x8 ia0 = ldfrag(kjs + arow * PITCH + acol);
  bf16x8 ia1 = ldfrag(kjs + arow * PITCH + acol + 32);

  floatx4 oacc[4];
  #pragma unroll
  for (int c = 0; c < 4; ++c) oacc[c] = (floatx4){0.f, 0.f, 0.f, 0.f};
  float m_i[4] = { -1e30f, -1e30f, -1e30f, -1e30f };
  float l_i[4] = { 0.f, 0.f, 0.f, 0.f };

  for (int j0 = 0; j0 < S_LEN; j0 += 64) {
    __syncthreads();   // B1: prior reads of kjs/vts (incl. pre-loop frag loads) done

    // ---- stage K_j ----
    {
      const float* gk = k + (size_t)j0 * BHD + bh * D_DIM;
      for (int idx = tid; idx < 1024; idx += 256) {
        int row = idx >> 4, cg = (idx & 15) << 2;
        float4 b = *(const float4*)(gk + row * BHD + cg);
        *(ushort4*)(kjs + row * PITCH + cg) = (ushort4){ f2bf(b.x), f2bf(b.y), f2bf(b.z), f2bf(b.w) };
      }
    }
    // ---- stage V^T: vts[d][j] ----
    {
      const float* gv = v + (size_t)j0 * BHD + bh * D_DIM;
      for (int idx = tid; idx < 1024; idx += 256) {
        int dg = idx & 15, jl = idx >> 4;
        float4 b = *(const float4*)(gv + jl * BHD + dg * 4);
        int d0 = dg * 4;
        vts[(d0 + 0) * PITCH + jl] = f2bf(b.x);
        vts[(d0 + 1) * PITCH + jl] = f2bf(b.y);
        vts[(d0 + 2) * PITCH + jl] = f2bf(b.z);
        vts[(d0 + 3) * PITCH + jl] = f2bf(b.w);
      }
    }

    // ---- bias MFMAs (no LDS dependency: ia regs + emb from global/L2) ----
    floatx4 bacc[5];
    {
      const int rbase = j0 - i0 + 448;
      #pragma unroll
      for (int ei = 0; ei < 5; ++ei) {
        int rg = rbase + (elo + ei) * 16 + l15;
        rg = min(rg, R_LEN - 1);                       // clamp touches only unused lanes
        const float* ep = emb + ((size_t)h * R_LEN + rg) * D_DIM + acol;
        float4 e0 = *(const float4*)(ep);
        float4 e1 = *(const float4*)(ep + 4);
        float4 e2 = *(const float4*)(ep + 32);
        float4 e3 = *(const float4*)(ep + 36);
        floatx4 bz = (floatx4){0.f, 0.f, 0.f, 0.f};
        bz = __builtin_amdgcn_mfma_f32_16x16x32_bf16(ia0, pack8(e0, e1), bz, 0, 0, 0);
        bz = __builtin_amdgcn_mfma_f32_16x16x32_bf16(ia1, pack8(e2, e3), bz, 0, 0, 0);
        bacc[ei] = bz;
      }
    }
    __syncthreads();   // B2: staging visible

    // ---- QK^T ----
    floatx4 qk[4];
    #pragma unroll
    for (int c = 0; c < 4; ++c) {
      bf16x8 kb0 = ldfrag(kjs + (c * 16 + l15) * PITCH + acol);
      bf16x8 kb1 = ldfrag(kjs + (c * 16 + l15) * PITCH + acol + 32);
      floatx4 acc = (floatx4){0.f, 0.f, 0.f, 0.f};
      acc = __builtin_amdgcn_mfma_f32_16x16x32_bf16(qa0, kb0, acc, 0, 0, 0);
      acc = __builtin_amdgcn_mfma_f32_16x16x32_bf16(qa1, kb1, acc, 0, 0, 0);
      qk[c] = acc;
    }

    // ---- add bias via skew-shuffle: bias[iloc][jl] lives at e=c(+1), lane (l15+o)&15 ----
    float sc[4][4];
    #pragma unroll
    for (int r = 0; r < 4; ++r) {
      const int o  = 15 - 4 * quad - r;                 // (63 - iloc) & 15
      const int ls = (lane & 48) + ((l15 + o) & 15);
      const bool hi = (l15 + o) >= 16;
      #pragma unroll
      for (int c = 0; c < 4; ++c) {
        float blo = __shfl(bacc[c][r],     ls);
        float bhi = __shfl(bacc[c + 1][r], ls);
        sc[c][r] = (qk[c][r] + (hi ? bhi : blo)) * 0.125f;
      }
    }

    // ---- online softmax (rows live in 16-lane quads) ----
    float p[4][4];
    #pragma unroll
    for (int r = 0; r < 4; ++r) {
      float mx = fmaxf(fmaxf(sc[0][r], sc[1][r]), fmaxf(sc[2][r], sc[3][r]));
      #pragma unroll
      for (int off = 1; off < 16; off <<= 1) mx = fmaxf(mx, __shfl_xor(mx, off));
      float mnew  = fmaxf(m_i[r], mx);
      float alpha = __expf(m_i[r] - mnew);
      float rs = 0.f;
      #pragma unroll
      for (int c = 0; c < 4; ++c) { p[c][r] = __expf(sc[c][r] - mnew); rs += p[c][r]; }
      #pragma unroll
      for (int off = 1; off < 16; off <<= 1) rs += __shfl_xor(rs, off);
      l_i[r] = l_i[r] * alpha + rs;
      m_i[r] = mnew;
      #pragma unroll
      for (int c = 0; c < 4; ++c) oacc[c][r] *= alpha;
    }

    // ---- P round-trip through wave-private LDS (no barrier needed) ----
    unsigned short* psw = ps[wv];
    #pragma unroll
    for (int c = 0; c < 4; ++c) {
      #pragma unroll
      for (int r = 0; r < 4; ++r)
        psw[(quad * 4 + r) * PPITCH + c * 16 + l15] = f2bf(p[c][r]);
    }
    bf16x8 pa0 = ldfrag8(psw + l15 * PPITCH + acol);
    bf16x8 pa1 = ldfrag8(psw + l15 * PPITCH + acol + 32);
    #pragma unroll
    for (int c = 0; c < 4; ++c) {
      bf16x8 vb0 = ldfrag(vts + (c * 16 + l15) * PITCH + acol);
      bf16x8 vb1 = ldfrag(vts + (c * 16 + l15) * PITCH + acol + 32);
      oacc[c] = __builtin_amdgcn_mfma_f32_16x16x32_bf16(pa0, vb0, oacc[c], 0, 0, 0);
      oacc[c] = __builtin_amdgcn_mfma_f32_16x16x32_bf16(pa1, vb1, oacc[c], 0, 0, 0);
    }
  }

  // ---- epilogue ----
  #pragma unroll
  for (int r = 0; r < 4; ++r) {
    float inv = 1.f / l_i[r];
    int row = i0 + iloc0 + r;
    #pragma unroll
    for (int c = 0; c < 4; ++c)
      out[(size_t)row * BHD + bh * D_DIM + c * 16 + l15] = oacc[c][r] * inv;
  }
}

extern "C" void kernel_launch(void* const* d_in, const int* in_sizes, int n_in,
                              void* d_out, int out_size, void* d_ws, size_t ws_size,
                              hipStream_t stream) {
  const float* q   = (const float*)d_in[0];
  const float* k   = (const float*)d_in[1];
  const float* v   = (const float*)d_in[2];
  const float* emb = (const float*)d_in[3];
  float* out = (float*)d_out;
  hipLaunchKernelGGL(attn_relbias, dim3(2048), dim3(256), 0, stream,
                     q, k, v, emb, out);
}